// Round 1
// baseline (484.467 us; speedup 1.0000x reference)
//
#include <hip/hip_runtime.h>
#include <math.h>

#define F 32
#define FC 64   // combined z|h feature width
#define SCAN_CHUNK 1024

// ---------------- weight folding: Mz = Wz @ Lz_W[:32], Mh = Wh @ Lh_W[:32]
__global__ void k_prep(const float* __restrict__ Wz, const float* __restrict__ Wh,
                       const float* __restrict__ LzW, const float* __restrict__ LhW,
                       const float* __restrict__ bz, const float* __restrict__ bh,
                       const float* __restrict__ Lzb, const float* __restrict__ Lhb,
                       float* __restrict__ Mcomb, float* __restrict__ czh) {
  int t = threadIdx.x;
  for (int idx = t; idx < F * FC; idx += blockDim.x) {
    int k = idx / FC;
    int j = idx % FC;
    float s = 0.f;
    if (j < F) {
      for (int m = 0; m < F; ++m) s = fmaf(Wz[k * F + m], LzW[m * F + j], s);
    } else {
      int jj = j - F;
      for (int m = 0; m < F; ++m) s = fmaf(Wh[k * F + m], LhW[m * F + jj], s);
    }
    Mcomb[idx] = s;
  }
  if (t < FC) {
    float s;
    if (t < F) {
      s = Lzb[t];
      for (int k = 0; k < F; ++k) s = fmaf(bz[k], LzW[k * F + t], s);
    } else {
      int jj = t - F;
      s = Lhb[jj];
      for (int k = 0; k < F; ++k) s = fmaf(bh[k], LhW[k * F + jj], s);
    }
    czh[t] = s;
  }
}

// ---------------- init: deg = 1 (self-loop), cnt = 0; offs[N] = E
__global__ void k_init(float* __restrict__ deg, int* __restrict__ cnt,
                       int* __restrict__ offs, int n, int e_total) {
  int i = blockIdx.x * blockDim.x + threadIdx.x;
  if (i < n) { deg[i] = 1.0f; cnt[i] = 0; }
  if (i == 0) offs[n] = e_total;
}

// ---------------- edge pass 1: weighted in-degree + histogram by col
__global__ void k_edge1(const int* __restrict__ ei, const float* __restrict__ ew,
                        float* __restrict__ deg, int* __restrict__ cnt, int e_total) {
  int e = blockIdx.x * blockDim.x + threadIdx.x;
  if (e >= e_total) return;
  int c = ei[e_total + e];
  atomicAdd(&deg[c], ew[e]);
  atomicAdd(&cnt[c], 1);
}

// ---------------- dinv = rsqrt(deg) in place
__global__ void k_dinv(float* __restrict__ deg, int n) {
  int i = blockIdx.x * blockDim.x + threadIdx.x;
  if (i >= n) return;
  float d = deg[i];
  deg[i] = (d > 0.f) ? rsqrtf(d) : 0.f;
}

// ---------------- XW[i][j] = sum_k x[i][k] * Mcomb[k][j]  (wave per node)
__global__ void k_xw(const float* __restrict__ x, const float* __restrict__ Mcomb,
                     float* __restrict__ XW, int n) {
  __shared__ float M[F * FC];
  for (int u = threadIdx.x; u < F * FC; u += blockDim.x) M[u] = Mcomb[u];
  __syncthreads();
  int gw = (blockIdx.x * blockDim.x + threadIdx.x) >> 6;
  int j = threadIdx.x & 63;
  if (gw >= n) return;
  const float* xr = x + (size_t)gw * F;
  float acc = 0.f;
#pragma unroll
  for (int k = 0; k < F; ++k) acc = fmaf(xr[k], M[k * FC + j], acc);
  XW[(size_t)gw * FC + j] = acc;
}

// ---------------- scan stage 1: per-chunk sums
__global__ void k_bsum(const int* __restrict__ cnt, int* __restrict__ bsum, int n) {
  __shared__ int s[SCAN_CHUNK];
  int t = threadIdx.x;
  int i = blockIdx.x * SCAN_CHUNK + t;
  s[t] = (i < n) ? cnt[i] : 0;
  __syncthreads();
  for (int d = SCAN_CHUNK / 2; d > 0; d >>= 1) {
    if (t < d) s[t] += s[t + d];
    __syncthreads();
  }
  if (t == 0) bsum[blockIdx.x] = s[0];
}

// ---------------- scan stage 2: exclusive scan of chunk sums (single block)
__global__ void k_bscan(int* __restrict__ bsum, int nb) {
  __shared__ int s[2][128];
  int t = threadIdx.x;
  int v = (t < nb) ? bsum[t] : 0;
  s[0][t] = v;
  __syncthreads();
  int src = 0;
  for (int d = 1; d < 128; d <<= 1) {
    int val = s[src][t];
    if (t >= d) val += s[src][t - d];
    s[src ^ 1][t] = val;
    src ^= 1;
    __syncthreads();
  }
  if (t < nb) bsum[t] = s[src][t] - v;  // exclusive
}

// ---------------- scan stage 3: per-chunk exclusive scan + chunk offset
__global__ void k_offs(const int* __restrict__ cnt, const int* __restrict__ bsum,
                       int* __restrict__ offs, int* __restrict__ cursor, int n) {
  __shared__ int s[2][SCAN_CHUNK];
  int t = threadIdx.x;
  int i = blockIdx.x * SCAN_CHUNK + t;
  int v = (i < n) ? cnt[i] : 0;
  s[0][t] = v;
  __syncthreads();
  int src = 0;
  for (int d = 1; d < SCAN_CHUNK; d <<= 1) {
    int val = s[src][t];
    if (t >= d) val += s[src][t - d];
    s[src ^ 1][t] = val;
    src ^= 1;
    __syncthreads();
  }
  if (i < n) {
    int excl = s[src][t] - v + bsum[blockIdx.x];
    offs[i] = excl;
    cursor[i] = excl;
  }
}

// ---------------- CSR scatter: edge -> (srcrow, w = dinv[row]*ew)
__global__ void k_scatter(const int* __restrict__ ei, const float* __restrict__ ew,
                          const float* __restrict__ dinv, int* __restrict__ cursor,
                          int* __restrict__ srcrow, float* __restrict__ wsrc, int e_total) {
  int e = blockIdx.x * blockDim.x + threadIdx.x;
  if (e >= e_total) return;
  int r = ei[e];
  int c = ei[e_total + e];
  float w = dinv[r] * ew[e];
  int pos = atomicAdd(&cursor[c], 1);
  srcrow[pos] = r;
  wsrc[pos] = w;
}

// ---------------- fused gather + gates + output (wave per node)
__global__ void k_agg(const float* __restrict__ XW, const float* __restrict__ dinv,
                      const int* __restrict__ offs, const int* __restrict__ srcrow,
                      const float* __restrict__ wsrc, const float* __restrict__ czh,
                      const float* __restrict__ linW, const float* __restrict__ linb,
                      float* __restrict__ out, int n) {
  int wid = (blockIdx.x * blockDim.x + threadIdx.x) >> 6;
  int j = threadIdx.x & 63;
  if (wid >= n) return;
  float di = dinv[wid];
  float acc = di * XW[(size_t)wid * FC + j];  // self-loop (extra di applied at end)
  int b = offs[wid], e = offs[wid + 1];
  for (int t = b; t < e; ++t) {
    int r = srcrow[t];
    float w = wsrc[t];
    acc = fmaf(w, XW[(size_t)r * FC + j], acc);
  }
  acc *= di;
  float a = acc + czh[j];
  float g;
  if (j < 32) g = 1.0f / (1.0f + expf(-a));  // Z
  else        g = tanhf(a);                  // H_tilde
  int src = (j + 32) & 63;
  float other = __shfl(g, src, 64);
  float val = 0.f;
  if (j < 32) {
    float hn = (1.0f - g) * other;   // (1-Z)*H_tilde
    float h = fmaxf(hn, 0.f);        // relu
    val = h * linW[j];
  }
  for (int d = 32; d > 0; d >>= 1) val += __shfl_xor(val, d, 64);
  if (j == 0) out[wid] = val + linb[0];
}

extern "C" void kernel_launch(void* const* d_in, const int* in_sizes, int n_in,
                              void* d_out, int out_size, void* d_ws, size_t ws_size,
                              hipStream_t stream) {
  const float* x   = (const float*)d_in[0];
  const int*   ei  = (const int*)d_in[1];
  const float* ew  = (const float*)d_in[2];
  const float* Wz  = (const float*)d_in[3];
  const float* bz  = (const float*)d_in[4];
  // d_in[5], d_in[6]: Wr, br — dead (H = 0)
  const float* Wh  = (const float*)d_in[7];
  const float* bh  = (const float*)d_in[8];
  const float* LzW = (const float*)d_in[9];
  const float* Lzb = (const float*)d_in[10];
  // d_in[11], d_in[12]: Lr_W, Lr_b — dead
  const float* LhW = (const float*)d_in[13];
  const float* Lhb = (const float*)d_in[14];
  const float* lnW = (const float*)d_in[15];
  const float* lnb = (const float*)d_in[16];
  float* out = (float*)d_out;

  const int n = in_sizes[0] / F;
  const int e_total = in_sizes[2];
  const int nb = (n + SCAN_CHUNK - 1) / SCAN_CHUNK;

  char* p = (char*)d_ws;
  auto alloc = [&](size_t bytes) -> void* {
    void* q = (void*)p;
    p += (bytes + 255) & ~(size_t)255;
    return q;
  };
  float* Mcomb  = (float*)alloc((size_t)F * FC * 4);
  float* czh    = (float*)alloc(FC * 4);
  float* deg    = (float*)alloc((size_t)n * 4);       // becomes dinv
  int*   cnt    = (int*)alloc((size_t)n * 4);
  int*   offs   = (int*)alloc(((size_t)n + 1) * 4);
  int*   cursor = (int*)alloc((size_t)n * 4);
  int*   bsum   = (int*)alloc(128 * 4);
  float* XW     = (float*)alloc((size_t)n * FC * 4);
  int*   srcrow = (int*)alloc((size_t)e_total * 4);
  float* wsrc   = (float*)alloc((size_t)e_total * 4);

  dim3 blk(256);
  int gN = (n + 255) / 256;
  int gE = (e_total + 255) / 256;
  int gW = ((n * 64) + 255) / 256;  // wave-per-node kernels

  k_prep<<<1, 1024, 0, stream>>>(Wz, Wh, LzW, LhW, bz, bh, Lzb, Lhb, Mcomb, czh);
  k_init<<<gN, blk, 0, stream>>>(deg, cnt, offs, n, e_total);
  k_edge1<<<gE, blk, 0, stream>>>(ei, ew, deg, cnt, e_total);
  k_dinv<<<gN, blk, 0, stream>>>(deg, n);
  k_xw<<<gW, blk, 0, stream>>>(x, Mcomb, XW, n);
  k_bsum<<<nb, SCAN_CHUNK, 0, stream>>>(cnt, bsum, n);
  k_bscan<<<1, 128, 0, stream>>>(bsum, nb);
  k_offs<<<nb, SCAN_CHUNK, 0, stream>>>(cnt, bsum, offs, cursor, n);
  k_scatter<<<gE, blk, 0, stream>>>(ei, ew, deg, cursor, srcrow, wsrc, e_total);
  k_agg<<<gW, blk, 0, stream>>>(XW, deg, offs, srcrow, wsrc, czh, lnW, lnb, out, n);
}

// Round 2
// 407.888 us; speedup vs baseline: 1.1877x; 1.1877x over previous
//
#include <hip/hip_runtime.h>
#include <hip/hip_fp16.h>
#include <math.h>

#define F 32
#define FC 64   // combined z|h feature width
#define SCAN_CHUNK 1024

// ---------------- weight folding: Mcomb = [Wz@LzW_top | Wh@LhW_top], czh = folded bias
__global__ void k_prep(const float* __restrict__ Wz, const float* __restrict__ Wh,
                       const float* __restrict__ LzW, const float* __restrict__ LhW,
                       const float* __restrict__ bz, const float* __restrict__ bh,
                       const float* __restrict__ Lzb, const float* __restrict__ Lhb,
                       float* __restrict__ Mcomb, float* __restrict__ czh) {
  int t = threadIdx.x;
  for (int idx = t; idx < F * FC; idx += blockDim.x) {
    int k = idx / FC;
    int j = idx % FC;
    float s = 0.f;
    if (j < F) {
      for (int m = 0; m < F; ++m) s = fmaf(Wz[k * F + m], LzW[m * F + j], s);
    } else {
      int jj = j - F;
      for (int m = 0; m < F; ++m) s = fmaf(Wh[k * F + m], LhW[m * F + jj], s);
    }
    Mcomb[idx] = s;
  }
  if (t < FC) {
    float s;
    if (t < F) {
      s = Lzb[t];
      for (int k = 0; k < F; ++k) s = fmaf(bz[k], LzW[k * F + t], s);
    } else {
      int jj = t - F;
      s = Lhb[jj];
      for (int k = 0; k < F; ++k) s = fmaf(bh[k], LhW[k * F + jj], s);
    }
    czh[t] = s;
  }
}

// ---------------- init: deg = 1 (self-loop), cnt = 0; offs[N] = E
__global__ void k_init(float* __restrict__ deg, int* __restrict__ cnt,
                       int* __restrict__ offs, int n, int e_total) {
  int i = blockIdx.x * blockDim.x + threadIdx.x;
  if (i < n) { deg[i] = 1.0f; cnt[i] = 0; }
  if (i == 0) offs[n] = e_total;
}

// ---------------- edge pass 1: weighted in-degree + histogram by col
__global__ void k_edge1(const int* __restrict__ ei, const float* __restrict__ ew,
                        float* __restrict__ deg, int* __restrict__ cnt, int e_total) {
  int e = blockIdx.x * blockDim.x + threadIdx.x;
  if (e >= e_total) return;
  int c = ei[e_total + e];
  atomicAdd(&deg[c], ew[e]);
  atomicAdd(&cnt[c], 1);
}

// ---------------- dinv = rsqrt(deg) in place
__global__ void k_dinv(float* __restrict__ deg, int n) {
  int i = blockIdx.x * blockDim.x + threadIdx.x;
  if (i >= n) return;
  float d = deg[i];
  deg[i] = (d > 0.f) ? rsqrtf(d) : 0.f;
}

// ---------------- XW[i][j] = sum_k x[i][k] * Mcomb[k][j]  (wave per node, fp16 out)
__global__ void k_xw(const float* __restrict__ x, const float* __restrict__ Mcomb,
                     __half* __restrict__ XWh, int n) {
  __shared__ float M[F * FC];
  for (int u = threadIdx.x; u < F * FC; u += blockDim.x) M[u] = Mcomb[u];
  __syncthreads();
  int gw = (blockIdx.x * blockDim.x + threadIdx.x) >> 6;
  int j = threadIdx.x & 63;
  if (gw >= n) return;
  const float* xr = x + (size_t)gw * F;
  float acc = 0.f;
#pragma unroll
  for (int k = 0; k < F; ++k) acc = fmaf(xr[k], M[k * FC + j], acc);
  XWh[(size_t)gw * FC + j] = __float2half(acc);
}

// ---------------- scan stage 1: per-chunk sums
__global__ void k_bsum(const int* __restrict__ cnt, int* __restrict__ bsum, int n) {
  __shared__ int s[SCAN_CHUNK];
  int t = threadIdx.x;
  int i = blockIdx.x * SCAN_CHUNK + t;
  s[t] = (i < n) ? cnt[i] : 0;
  __syncthreads();
  for (int d = SCAN_CHUNK / 2; d > 0; d >>= 1) {
    if (t < d) s[t] += s[t + d];
    __syncthreads();
  }
  if (t == 0) bsum[blockIdx.x] = s[0];
}

// ---------------- scan stage 2: exclusive scan of chunk sums (single block)
__global__ void k_bscan(int* __restrict__ bsum, int nb) {
  __shared__ int s[2][128];
  int t = threadIdx.x;
  int v = (t < nb) ? bsum[t] : 0;
  s[0][t] = v;
  __syncthreads();
  int src = 0;
  for (int d = 1; d < 128; d <<= 1) {
    int val = s[src][t];
    if (t >= d) val += s[src][t - d];
    s[src ^ 1][t] = val;
    src ^= 1;
    __syncthreads();
  }
  if (t < nb) bsum[t] = s[src][t] - v;  // exclusive
}

// ---------------- scan stage 3: per-chunk exclusive scan + chunk offset
__global__ void k_offs(const int* __restrict__ cnt, const int* __restrict__ bsum,
                       int* __restrict__ offs, int* __restrict__ cursor, int n) {
  __shared__ int s[2][SCAN_CHUNK];
  int t = threadIdx.x;
  int i = blockIdx.x * SCAN_CHUNK + t;
  int v = (i < n) ? cnt[i] : 0;
  s[0][t] = v;
  __syncthreads();
  int src = 0;
  for (int d = 1; d < SCAN_CHUNK; d <<= 1) {
    int val = s[src][t];
    if (t >= d) val += s[src][t - d];
    s[src ^ 1][t] = val;
    src ^= 1;
    __syncthreads();
  }
  if (i < n) {
    int excl = s[src][t] - v + bsum[blockIdx.x];
    offs[i] = excl;
    cursor[i] = excl;
  }
}

// ---------------- CSR scatter: edge -> packed {srcrow, w = dinv[row]*ew} (one 8B store)
__global__ void k_scatter(const int* __restrict__ ei, const float* __restrict__ ew,
                          const float* __restrict__ dinv, int* __restrict__ cursor,
                          uint2* __restrict__ pk, int e_total) {
  int e = blockIdx.x * blockDim.x + threadIdx.x;
  if (e >= e_total) return;
  int r = ei[e];
  int c = ei[e_total + e];
  float w = dinv[r] * ew[e];
  int pos = atomicAdd(&cursor[c], 1);
  uint2 v;
  v.x = (unsigned)r;
  v.y = __float_as_uint(w);
  pk[pos] = v;
}

// ---------------- fused gather + gates + output (wave per node, fp16 XW)
__global__ void k_agg(const __half* __restrict__ XWh, const float* __restrict__ dinv,
                      const int* __restrict__ offs, const uint2* __restrict__ pk,
                      const float* __restrict__ czh,
                      const float* __restrict__ linW, const float* __restrict__ linb,
                      float* __restrict__ out, int n) {
  int wid = (blockIdx.x * blockDim.x + threadIdx.x) >> 6;
  int j = threadIdx.x & 63;
  if (wid >= n) return;
  float di = dinv[wid];
  float acc0 = di * __half2float(XWh[(size_t)wid * FC + j]);  // self-loop
  float acc1 = 0.f;
  int b = offs[wid], e = offs[wid + 1];
  int t = b;
  for (; t + 2 <= e; t += 2) {
    uint2 p0 = pk[t];
    uint2 p1 = pk[t + 1];
    float v0 = __half2float(XWh[(size_t)p0.x * FC + j]);
    float v1 = __half2float(XWh[(size_t)p1.x * FC + j]);
    acc0 = fmaf(__uint_as_float(p0.y), v0, acc0);
    acc1 = fmaf(__uint_as_float(p1.y), v1, acc1);
  }
  if (t < e) {
    uint2 p0 = pk[t];
    acc0 = fmaf(__uint_as_float(p0.y), __half2float(XWh[(size_t)p0.x * FC + j]), acc0);
  }
  float acc = (acc0 + acc1) * di;
  float a = acc + czh[j];
  float g;
  if (j < 32) g = 1.0f / (1.0f + expf(-a));  // Z
  else        g = tanhf(a);                  // H_tilde
  int src = (j + 32) & 63;
  float other = __shfl(g, src, 64);
  float val = 0.f;
  if (j < 32) {
    float hn = (1.0f - g) * other;   // (1-Z)*H_tilde
    float h = fmaxf(hn, 0.f);        // relu
    val = h * linW[j];
  }
  for (int d = 32; d > 0; d >>= 1) val += __shfl_xor(val, d, 64);
  if (j == 0) out[wid] = val + linb[0];
}

extern "C" void kernel_launch(void* const* d_in, const int* in_sizes, int n_in,
                              void* d_out, int out_size, void* d_ws, size_t ws_size,
                              hipStream_t stream) {
  const float* x   = (const float*)d_in[0];
  const int*   ei  = (const int*)d_in[1];
  const float* ew  = (const float*)d_in[2];
  const float* Wz  = (const float*)d_in[3];
  const float* bz  = (const float*)d_in[4];
  // d_in[5], d_in[6]: Wr, br — dead (H = 0)
  const float* Wh  = (const float*)d_in[7];
  const float* bh  = (const float*)d_in[8];
  const float* LzW = (const float*)d_in[9];
  const float* Lzb = (const float*)d_in[10];
  // d_in[11], d_in[12]: Lr_W, Lr_b — dead
  const float* LhW = (const float*)d_in[13];
  const float* Lhb = (const float*)d_in[14];
  const float* lnW = (const float*)d_in[15];
  const float* lnb = (const float*)d_in[16];
  float* out = (float*)d_out;

  const int n = in_sizes[0] / F;
  const int e_total = in_sizes[2];
  const int nb = (n + SCAN_CHUNK - 1) / SCAN_CHUNK;

  char* p = (char*)d_ws;
  auto alloc = [&](size_t bytes) -> void* {
    void* q = (void*)p;
    p += (bytes + 255) & ~(size_t)255;
    return q;
  };
  float* Mcomb  = (float*)alloc((size_t)F * FC * 4);
  float* czh    = (float*)alloc(FC * 4);
  float* deg    = (float*)alloc((size_t)n * 4);       // becomes dinv
  int*   cnt    = (int*)alloc((size_t)n * 4);
  int*   offs   = (int*)alloc(((size_t)n + 1) * 4);
  int*   cursor = (int*)alloc((size_t)n * 4);
  int*   bsum   = (int*)alloc(128 * 4);
  __half* XWh   = (__half*)alloc((size_t)n * FC * 2);
  uint2* pk     = (uint2*)alloc((size_t)e_total * 8);

  dim3 blk(256);
  int gN = (n + 255) / 256;
  int gE = (e_total + 255) / 256;
  int gW = ((n * 64) + 255) / 256;  // wave-per-node kernels

  k_prep<<<1, 1024, 0, stream>>>(Wz, Wh, LzW, LhW, bz, bh, Lzb, Lhb, Mcomb, czh);
  k_init<<<gN, blk, 0, stream>>>(deg, cnt, offs, n, e_total);
  k_edge1<<<gE, blk, 0, stream>>>(ei, ew, deg, cnt, e_total);
  k_dinv<<<gN, blk, 0, stream>>>(deg, n);
  k_xw<<<gW, blk, 0, stream>>>(x, Mcomb, XWh, n);
  k_bsum<<<nb, SCAN_CHUNK, 0, stream>>>(cnt, bsum, n);
  k_bscan<<<1, 128, 0, stream>>>(bsum, nb);
  k_offs<<<nb, SCAN_CHUNK, 0, stream>>>(cnt, bsum, offs, cursor, n);
  k_scatter<<<gE, blk, 0, stream>>>(ei, ew, deg, cursor, pk, e_total);
  k_agg<<<gW, blk, 0, stream>>>(XWh, deg, offs, pk, czh, lnW, lnb, out, n);
}

// Round 3
// 240.959 us; speedup vs baseline: 2.0106x; 1.6928x over previous
//
#include <hip/hip_runtime.h>
#include <hip/hip_fp16.h>
#include <math.h>

#define F 32
#define FC 64   // combined z|h feature width
#define SCAN_CHUNK 1024

// ---------------- weight folding: Mcomb = [Wz@LzW_top | Wh@LhW_top], czh = folded bias
__global__ void k_prep(const float* __restrict__ Wz, const float* __restrict__ Wh,
                       const float* __restrict__ LzW, const float* __restrict__ LhW,
                       const float* __restrict__ bz, const float* __restrict__ bh,
                       const float* __restrict__ Lzb, const float* __restrict__ Lhb,
                       float* __restrict__ Mcomb, float* __restrict__ czh) {
  int t = threadIdx.x;
  for (int idx = t; idx < F * FC; idx += blockDim.x) {
    int k = idx / FC;
    int j = idx % FC;
    float s = 0.f;
    if (j < F) {
      for (int m = 0; m < F; ++m) s = fmaf(Wz[k * F + m], LzW[m * F + j], s);
    } else {
      int jj = j - F;
      for (int m = 0; m < F; ++m) s = fmaf(Wh[k * F + m], LhW[m * F + jj], s);
    }
    Mcomb[idx] = s;
  }
  if (t < FC) {
    float s;
    if (t < F) {
      s = Lzb[t];
      for (int k = 0; k < F; ++k) s = fmaf(bz[k], LzW[k * F + t], s);
    } else {
      int jj = t - F;
      s = Lhb[jj];
      for (int k = 0; k < F; ++k) s = fmaf(bh[k], LhW[k * F + jj], s);
    }
    czh[t] = s;
  }
}

// ---------------- init: deg64 = 0; offs[N] = E
__global__ void k_init(unsigned long long* __restrict__ deg64,
                       int* __restrict__ offs, int n, int e_total) {
  int i = blockIdx.x * blockDim.x + threadIdx.x;
  if (i < n) deg64[i] = 0ull;
  if (i == 0) offs[n] = e_total;
}

// ---------------- edge pass 1: ONE packed 64b atomic per edge
//   low 48 bits: sum of w in 2^-32 fixed point; bits 48+: count.
//   returned old value's count field = this edge's rank within its col.
__global__ void k_edge1(const int* __restrict__ ei, const float* __restrict__ ew,
                        unsigned long long* __restrict__ deg64,
                        unsigned short* __restrict__ rank, int e_total) {
  int e = blockIdx.x * blockDim.x + threadIdx.x;
  if (e >= e_total) return;
  int c = ei[e_total + e];
  float w = ew[e];
  unsigned long long fx = (unsigned long long)((double)w * 4294967296.0);
  unsigned long long old = atomicAdd(&deg64[c], fx + (1ull << 48));
  rank[e] = (unsigned short)(old >> 48);
}

// ---------------- unpack: dinv = rsqrt(1 + fixsum), cnt = count
__global__ void k_dinv(const unsigned long long* __restrict__ deg64,
                       float* __restrict__ dinv, int* __restrict__ cnt, int n) {
  int i = blockIdx.x * blockDim.x + threadIdx.x;
  if (i >= n) return;
  unsigned long long v = deg64[i];
  cnt[i] = (int)(v >> 48);
  double s = 1.0 + (double)(v & 0xFFFFFFFFFFFFull) * (1.0 / 4294967296.0);
  dinv[i] = rsqrtf((float)s);
}

// ---------------- XW[i][j] = sum_k x[i][k] * Mcomb[k][j]  (wave per node, fp16 out)
__global__ void k_xw(const float* __restrict__ x, const float* __restrict__ Mcomb,
                     __half* __restrict__ XWh, int n) {
  __shared__ float M[F * FC];
  for (int u = threadIdx.x; u < F * FC; u += blockDim.x) M[u] = Mcomb[u];
  __syncthreads();
  int gw = (blockIdx.x * blockDim.x + threadIdx.x) >> 6;
  int j = threadIdx.x & 63;
  if (gw >= n) return;
  const float* xr = x + (size_t)gw * F;
  float acc = 0.f;
#pragma unroll
  for (int k = 0; k < F; ++k) acc = fmaf(xr[k], M[k * FC + j], acc);
  XWh[(size_t)gw * FC + j] = __float2half(acc);
}

// ---------------- scan stage 1: per-chunk sums
__global__ void k_bsum(const int* __restrict__ cnt, int* __restrict__ bsum, int n) {
  __shared__ int s[SCAN_CHUNK];
  int t = threadIdx.x;
  int i = blockIdx.x * SCAN_CHUNK + t;
  s[t] = (i < n) ? cnt[i] : 0;
  __syncthreads();
  for (int d = SCAN_CHUNK / 2; d > 0; d >>= 1) {
    if (t < d) s[t] += s[t + d];
    __syncthreads();
  }
  if (t == 0) bsum[blockIdx.x] = s[0];
}

// ---------------- scan stage 2: exclusive scan of chunk sums (single block)
__global__ void k_bscan(int* __restrict__ bsum, int nb) {
  __shared__ int s[2][128];
  int t = threadIdx.x;
  int v = (t < nb) ? bsum[t] : 0;
  s[0][t] = v;
  __syncthreads();
  int src = 0;
  for (int d = 1; d < 128; d <<= 1) {
    int val = s[src][t];
    if (t >= d) val += s[src][t - d];
    s[src ^ 1][t] = val;
    src ^= 1;
    __syncthreads();
  }
  if (t < nb) bsum[t] = s[src][t] - v;  // exclusive
}

// ---------------- scan stage 3: per-chunk exclusive scan + chunk offset
__global__ void k_offs(const int* __restrict__ cnt, const int* __restrict__ bsum,
                       int* __restrict__ offs, int n) {
  __shared__ int s[2][SCAN_CHUNK];
  int t = threadIdx.x;
  int i = blockIdx.x * SCAN_CHUNK + t;
  int v = (i < n) ? cnt[i] : 0;
  s[0][t] = v;
  __syncthreads();
  int src = 0;
  for (int d = 1; d < SCAN_CHUNK; d <<= 1) {
    int val = s[src][t];
    if (t >= d) val += s[src][t - d];
    s[src ^ 1][t] = val;
    src ^= 1;
    __syncthreads();
  }
  if (i < n) offs[i] = s[src][t] - v + bsum[blockIdx.x];
}

// ---------------- CSR scatter (NO atomics): pos = offs[col] + rank
__global__ void k_scatter(const int* __restrict__ ei, const float* __restrict__ ew,
                          const float* __restrict__ dinv, const int* __restrict__ offs,
                          const unsigned short* __restrict__ rank,
                          uint2* __restrict__ pk, int e_total) {
  int e = blockIdx.x * blockDim.x + threadIdx.x;
  if (e >= e_total) return;
  int r = ei[e];
  int c = ei[e_total + e];
  float w = dinv[r] * ew[e];
  int pos = offs[c] + (int)rank[e];
  uint2 v;
  v.x = (unsigned)r;
  v.y = __float_as_uint(w);
  pk[pos] = v;
}

// ---------------- fused gather + gates + output (wave per node, fp16 XW)
__global__ void k_agg(const __half* __restrict__ XWh, const float* __restrict__ dinv,
                      const int* __restrict__ offs, const uint2* __restrict__ pk,
                      const float* __restrict__ czh,
                      const float* __restrict__ linW, const float* __restrict__ linb,
                      float* __restrict__ out, int n) {
  int wid = (blockIdx.x * blockDim.x + threadIdx.x) >> 6;
  int j = threadIdx.x & 63;
  if (wid >= n) return;
  float di = dinv[wid];
  float acc0 = di * __half2float(XWh[(size_t)wid * FC + j]);  // self-loop
  float acc1 = 0.f;
  int b = offs[wid], e = offs[wid + 1];
  int t = b;
  for (; t + 4 <= e; t += 4) {
    uint2 p0 = pk[t];
    uint2 p1 = pk[t + 1];
    uint2 p2 = pk[t + 2];
    uint2 p3 = pk[t + 3];
    float v0 = __half2float(XWh[(size_t)p0.x * FC + j]);
    float v1 = __half2float(XWh[(size_t)p1.x * FC + j]);
    float v2 = __half2float(XWh[(size_t)p2.x * FC + j]);
    float v3 = __half2float(XWh[(size_t)p3.x * FC + j]);
    acc0 = fmaf(__uint_as_float(p0.y), v0, acc0);
    acc1 = fmaf(__uint_as_float(p1.y), v1, acc1);
    acc0 = fmaf(__uint_as_float(p2.y), v2, acc0);
    acc1 = fmaf(__uint_as_float(p3.y), v3, acc1);
  }
  for (; t < e; ++t) {
    uint2 p0 = pk[t];
    acc0 = fmaf(__uint_as_float(p0.y), __half2float(XWh[(size_t)p0.x * FC + j]), acc0);
  }
  float acc = (acc0 + acc1) * di;
  float a = acc + czh[j];
  float g;
  if (j < 32) g = 1.0f / (1.0f + expf(-a));  // Z
  else        g = tanhf(a);                  // H_tilde
  int src = (j + 32) & 63;
  float other = __shfl(g, src, 64);
  float val = 0.f;
  if (j < 32) {
    float hn = (1.0f - g) * other;   // (1-Z)*H_tilde
    float h = fmaxf(hn, 0.f);        // relu
    val = h * linW[j];
  }
  for (int d = 32; d > 0; d >>= 1) val += __shfl_xor(val, d, 64);
  if (j == 0) out[wid] = val + linb[0];
}

extern "C" void kernel_launch(void* const* d_in, const int* in_sizes, int n_in,
                              void* d_out, int out_size, void* d_ws, size_t ws_size,
                              hipStream_t stream) {
  const float* x   = (const float*)d_in[0];
  const int*   ei  = (const int*)d_in[1];
  const float* ew  = (const float*)d_in[2];
  const float* Wz  = (const float*)d_in[3];
  const float* bz  = (const float*)d_in[4];
  // d_in[5], d_in[6]: Wr, br — dead (H = 0)
  const float* Wh  = (const float*)d_in[7];
  const float* bh  = (const float*)d_in[8];
  const float* LzW = (const float*)d_in[9];
  const float* Lzb = (const float*)d_in[10];
  // d_in[11], d_in[12]: Lr_W, Lr_b — dead
  const float* LhW = (const float*)d_in[13];
  const float* Lhb = (const float*)d_in[14];
  const float* lnW = (const float*)d_in[15];
  const float* lnb = (const float*)d_in[16];
  float* out = (float*)d_out;

  const int n = in_sizes[0] / F;
  const int e_total = in_sizes[2];
  const int nb = (n + SCAN_CHUNK - 1) / SCAN_CHUNK;

  char* p = (char*)d_ws;
  auto alloc = [&](size_t bytes) -> void* {
    void* q = (void*)p;
    p += (bytes + 255) & ~(size_t)255;
    return q;
  };
  float* Mcomb  = (float*)alloc((size_t)F * FC * 4);
  float* czh    = (float*)alloc(FC * 4);
  unsigned long long* deg64 = (unsigned long long*)alloc((size_t)n * 8);
  float* dinv   = (float*)alloc((size_t)n * 4);
  int*   cnt    = (int*)alloc((size_t)n * 4);
  int*   offs   = (int*)alloc(((size_t)n + 1) * 4);
  int*   bsum   = (int*)alloc(128 * 4);
  unsigned short* rank = (unsigned short*)alloc((size_t)e_total * 2);
  __half* XWh   = (__half*)alloc((size_t)n * FC * 2);
  uint2* pk     = (uint2*)alloc((size_t)e_total * 8);

  dim3 blk(256);
  int gN = (n + 255) / 256;
  int gE = (e_total + 255) / 256;
  int gW = ((n * 64) + 255) / 256;  // wave-per-node kernels

  k_prep<<<1, 1024, 0, stream>>>(Wz, Wh, LzW, LhW, bz, bh, Lzb, Lhb, Mcomb, czh);
  k_init<<<gN, blk, 0, stream>>>(deg64, offs, n, e_total);
  k_edge1<<<gE, blk, 0, stream>>>(ei, ew, deg64, rank, e_total);
  k_dinv<<<gN, blk, 0, stream>>>(deg64, dinv, cnt, n);
  k_xw<<<gW, blk, 0, stream>>>(x, Mcomb, XWh, n);
  k_bsum<<<nb, SCAN_CHUNK, 0, stream>>>(cnt, bsum, n);
  k_bscan<<<1, 128, 0, stream>>>(bsum, nb);
  k_offs<<<nb, SCAN_CHUNK, 0, stream>>>(cnt, bsum, offs, n);
  k_scatter<<<gE, blk, 0, stream>>>(ei, ew, dinv, offs, rank, pk, e_total);
  k_agg<<<gW, blk, 0, stream>>>(XWh, dinv, offs, pk, czh, lnW, lnb, out, n);
}